// Round 5
// baseline (472.287 us; speedup 1.0000x reference)
//
#include <hip/hip_runtime.h>
#include <hip/hip_bf16.h>
#include <stdint.h>
#include <stddef.h>

#define Bdim  32
#define Sdim  1024
#define Hdim  1024
#define Wdim  128
#define Ktok  6
#define NHEAD 16
#define HDdim 64
#define Lgrp  (Bdim*Wdim)      // 4096 groups
#define Mrows (Lgrp*Ktok)      // 24576 gathered rows
#define Ncols (2*Hdim)         // 2048 (q|k)
#define CVTROWS (Mrows + Ncols) // gather rows + weight rows

typedef __attribute__((ext_vector_type(8))) short short8;
typedef __attribute__((ext_vector_type(4))) short short4_t;
typedef __attribute__((ext_vector_type(4))) float floatx4;
typedef __hip_bfloat16 bf16_t;

typedef unsigned int u32_g __attribute__((address_space(1)));
typedef unsigned int u32_l __attribute__((address_space(3)));

__device__ __forceinline__ void gld_lds16(const void* g, void* l) {
    __builtin_amdgcn_global_load_lds((const u32_g*)g, (u32_l*)l, 16, 0, 0);
}

__device__ __forceinline__ float b2f(short s) {
    union { float f; unsigned u; } x; x.u = ((unsigned)(unsigned short)s) << 16; return x.f;
}

// pack 8 fp32 -> 8 bf16 (RNE) in a 16B vector
__device__ __forceinline__ short8 cvt8(const float4 lo, const float4 hi) {
    union { short8 s; bf16_t h[8]; } u;
    u.h[0] = __float2bfloat16(lo.x); u.h[1] = __float2bfloat16(lo.y);
    u.h[2] = __float2bfloat16(lo.z); u.h[3] = __float2bfloat16(lo.w);
    u.h[4] = __float2bfloat16(hi.x); u.h[5] = __float2bfloat16(hi.y);
    u.h[6] = __float2bfloat16(hi.z); u.h[7] = __float2bfloat16(hi.w);
    return u.s;
}

// ---------------------------------------------------------------------------
// Kernel 0: gather A rows + convert everything to bf16 once.
// ---------------------------------------------------------------------------
__global__ void gather_cvt(const float* __restrict__ TE, const float* __restrict__ Wt,
                           const int* __restrict__ sidx,
                           bf16_t* __restrict__ Xa, bf16_t* __restrict__ Wb)
{
    const int r = blockIdx.x;
    const int t = threadIdx.x;
    const float* src;
    bf16_t* dst;
    if (r < Mrows) {
        src = TE + ((size_t)(r/768)*Sdim + sidx[r])*Hdim;
        dst = Xa + (size_t)r*Hdim;
    } else {
        src = Wt + (size_t)(r - Mrows)*Hdim;
        dst = Wb + (size_t)(r - Mrows)*Hdim;
    }
    const float4 v = *(const float4*)(src + t*4);
    union { short4_t s; bf16_t h[4]; } u;
    u.h[0] = __float2bfloat16(v.x); u.h[1] = __float2bfloat16(v.y);
    u.h[2] = __float2bfloat16(v.z); u.h[3] = __float2bfloat16(v.w);
    *(short4_t*)(dst + t*4) = u.s;
}

// ---------------------------------------------------------------------------
// Kernel 1: pure-bf16 GEMM with XOR chunk swizzle (bank-conflict-free frags).
//   LDS[r][c] holds global chunk c ^ ((r>>1)&3); fragment for (row m, chunk fq)
//   reads LDS chunk fq ^ ((m>>1)&3). Staging LDS dest stays base + lane*16.
// ---------------------------------------------------------------------------
__global__ __launch_bounds__(256, 2) void gemm_bf16(
    const bf16_t* __restrict__ Xa, const bf16_t* __restrict__ Wb,
    const float* __restrict__ bias, bf16_t* __restrict__ Cq)
{
    __shared__ __align__(16) bf16_t As[128*32];
    __shared__ __align__(16) bf16_t Bs[128*32];
    const int tid  = threadIdx.x;
    const int wv   = tid >> 6;
    const int lane = tid & 63;
    const int tileM = blockIdx.x * 128;
    const int tileN = blockIdx.y * 128;

    const int r0 = wv*32 + (lane>>2);
    const int r1 = r0 + 16;                    // (r1>>1)&3 == (r0>>1)&3
    const int c  = lane & 3;
    const int cg = (c ^ ((r0 >> 1) & 3)) * 8;  // swizzled global chunk (elems)

    const bf16_t* pA0 = Xa + (size_t)(tileM + r0)*Hdim + cg;
    const bf16_t* pA1 = Xa + (size_t)(tileM + r1)*Hdim + cg;
    const bf16_t* pB0 = Wb + (size_t)(tileN + r0)*Hdim + cg;
    const bf16_t* pB1 = Wb + (size_t)(tileN + r1)*Hdim + cg;
    bf16_t* lA0 = &As[r0*32 + c*8];
    bf16_t* lA1 = &As[r1*32 + c*8];
    bf16_t* lB0 = &Bs[r0*32 + c*8];
    bf16_t* lB1 = &Bs[r1*32 + c*8];

    const int wm = (wv & 1)*64;
    const int wn = (wv >> 1)*64;
    const int fr = lane & 15;
    const int fq = lane >> 4;
    // (wm+mi*16+fr)>>1 & 3 == (fr>>1)&3  (wm, mi*16 are multiples of 8 in >>1)
    const int swzf = (fq ^ ((fr >> 1) & 3)) * 8;

    floatx4 acc[4][4] = {};

    for (int k0 = 0; k0 < Hdim; k0 += 32) {
        gld_lds16(pA0 + k0, lA0);
        gld_lds16(pA1 + k0, lA1);
        gld_lds16(pB0 + k0, lB0);
        gld_lds16(pB1 + k0, lB1);
        __syncthreads();
        short8 a[4], b[4];
        #pragma unroll
        for (int mi = 0; mi < 4; mi++)
            a[mi] = *(const short8*)(const void*)&As[(wm + mi*16 + fr)*32 + swzf];
        #pragma unroll
        for (int ni = 0; ni < 4; ni++)
            b[ni] = *(const short8*)(const void*)&Bs[(wn + ni*16 + fr)*32 + swzf];
        #pragma unroll
        for (int mi = 0; mi < 4; mi++)
            #pragma unroll
            for (int ni = 0; ni < 4; ni++)
                acc[mi][ni] = __builtin_amdgcn_mfma_f32_16x16x32_bf16(
                    a[mi], b[ni], acc[mi][ni], 0, 0, 0);
        __syncthreads();
    }

    #pragma unroll
    for (int ni = 0; ni < 4; ni++) {
        const int col = tileN + wn + ni*16 + fr;
        const float bv = bias[col];
        #pragma unroll
        for (int mi = 0; mi < 4; mi++) {
            #pragma unroll
            for (int r = 0; r < 4; r++) {
                const int row = tileM + wm + mi*16 + fq*4 + r;
                Cq[(size_t)row * Ncols + col] = __float2bfloat16(acc[mi][ni][r] + bv);
            }
        }
    }
}

// ---------------------------------------------------------------------------
// Kernel 1 (fallback, ws too small): round-3 fused gather+cvt GEMM.
// ---------------------------------------------------------------------------
__global__ __launch_bounds__(256, 2) void gemm_qk(
    const float* __restrict__ TE, const float* __restrict__ Wt,
    const float* __restrict__ bias, const int* __restrict__ sidx,
    bf16_t* __restrict__ Cq)
{
    __shared__ __align__(16) bf16_t As[128*32];
    __shared__ __align__(16) bf16_t Bs[128*32];
    const int tid  = threadIdx.x;
    const int wv   = tid >> 6;
    const int lane = tid & 63;
    const int tileM = blockIdx.x * 128;
    const int tileN = blockIdx.y * 128;

    const int r0 = wv*32 + (lane>>2);
    const int r1 = r0 + 16;
    const int c8 = (lane&3)*8;

    const int m0 = tileM + r0;
    const int m1 = tileM + r1;
    const float* pA0 = TE + ((size_t)(m0/768)*Sdim + sidx[m0])*Hdim + c8;
    const float* pA1 = TE + ((size_t)(m1/768)*Sdim + sidx[m1])*Hdim + c8;
    const float* pB0 = Wt + (size_t)(tileN + r0)*Hdim + c8;
    const float* pB1 = Wt + (size_t)(tileN + r1)*Hdim + c8;
    bf16_t* lA0 = &As[r0*32 + c8];
    bf16_t* lA1 = &As[r1*32 + c8];
    bf16_t* lB0 = &Bs[r0*32 + c8];
    bf16_t* lB1 = &Bs[r1*32 + c8];

    const int wm = (wv & 1)*64;
    const int wn = (wv >> 1)*64;
    const int fr = lane & 15;
    const int fq = lane >> 4;

    floatx4 acc[4][4] = {};

    for (int k0 = 0; k0 < Hdim; k0 += 32) {
        const float4 a0l = *(const float4*)(pA0 + k0);
        const float4 a0h = *(const float4*)(pA0 + k0 + 4);
        const float4 a1l = *(const float4*)(pA1 + k0);
        const float4 a1h = *(const float4*)(pA1 + k0 + 4);
        const float4 b0l = *(const float4*)(pB0 + k0);
        const float4 b0h = *(const float4*)(pB0 + k0 + 4);
        const float4 b1l = *(const float4*)(pB1 + k0);
        const float4 b1h = *(const float4*)(pB1 + k0 + 4);
        *(short8*)(void*)lA0 = cvt8(a0l, a0h);
        *(short8*)(void*)lA1 = cvt8(a1l, a1h);
        *(short8*)(void*)lB0 = cvt8(b0l, b0h);
        *(short8*)(void*)lB1 = cvt8(b1l, b1h);
        __syncthreads();
        short8 a[4], b[4];
        #pragma unroll
        for (int mi = 0; mi < 4; mi++)
            a[mi] = *(const short8*)(const void*)&As[(wm + mi*16 + fr)*32 + fq*8];
        #pragma unroll
        for (int ni = 0; ni < 4; ni++)
            b[ni] = *(const short8*)(const void*)&Bs[(wn + ni*16 + fr)*32 + fq*8];
        #pragma unroll
        for (int mi = 0; mi < 4; mi++)
            #pragma unroll
            for (int ni = 0; ni < 4; ni++)
                acc[mi][ni] = __builtin_amdgcn_mfma_f32_16x16x32_bf16(
                    a[mi], b[ni], acc[mi][ni], 0, 0, 0);
        __syncthreads();
    }

    #pragma unroll
    for (int ni = 0; ni < 4; ni++) {
        const int col = tileN + wn + ni*16 + fr;
        const float bv = bias[col];
        #pragma unroll
        for (int mi = 0; mi < 4; mi++) {
            #pragma unroll
            for (int r = 0; r < 4; r++) {
                const int row = tileM + wm + mi*16 + fq*4 + r;
                Cq[(size_t)row * Ncols + col] = __float2bfloat16(acc[mi][ni][r] + bv);
            }
        }
    }
}

// ---------------------------------------------------------------------------
// Kernel 2: per-group attention -> contrib weights only. CW[g*8+j], j<6.
// ---------------------------------------------------------------------------
__global__ __launch_bounds__(256) void attn_contrib(
    const bf16_t* __restrict__ Cq, const float* __restrict__ bias,
    const int* __restrict__ sidx, float* __restrict__ CW)
{
    __shared__ __align__(16) bf16_t qk[Ktok][Ncols];   // 24 KB bf16 q|k rows
    __shared__ float sc[NHEAD][Ktok][Ktok];
    __shared__ float cbS[Ktok];
    __shared__ int   validS[Ktok];

    const int g   = blockIdx.x;
    const int w   = g & (Wdim - 1);
    const int tid = threadIdx.x;

    if (tid < Ktok) {
        const int id = sidx[g*Ktok + tid];
        validS[tid] = (id != 0) || (w == 0 && tid == 0);
    }
    __syncthreads();

    int valid[Ktok];
    #pragma unroll
    for (int kk = 0; kk < Ktok; kk++) valid[kk] = validS[kk];

    // stage q|k rows into LDS as bf16 (bias substituted for invalid rows)
    #pragma unroll
    for (int it = 0; it < Ktok; it++) {
        if (valid[it]) {
            *(short8*)(void*)&qk[it][tid*8] =
                *(const short8*)(const void*)&Cq[(size_t)(g*Ktok + it)*Ncols + tid*8];
        } else {
            const float4 lo = *(const float4*)(bias + tid*8);
            const float4 hi = *(const float4*)(bias + tid*8 + 4);
            *(short8*)(void*)&qk[it][tid*8] = cvt8(lo, hi);
        }
    }
    __syncthreads();

    // scores[n][i][j] = q_i(head n) . k_j(head n) / 8 + pair
    for (int t = tid; t < NHEAD*Ktok*Ktok; t += 256) {
        const int n = t / (Ktok*Ktok);
        const int pr = t % (Ktok*Ktok);
        const int i = pr / Ktok, j = pr % Ktok;
        const bf16_t* qp = &qk[i][n*HDdim];
        const bf16_t* kp = &qk[j][Hdim + n*HDdim];
        float dot = 0.f;
        #pragma unroll
        for (int cc = 0; cc < 8; cc++) {
            const short8 q8 = *(const short8*)(const void*)(qp + cc*8);
            const short8 k8 = *(const short8*)(const void*)(kp + cc*8);
            #pragma unroll
            for (int e = 0; e < 8; e++) dot += b2f(q8[e]) * b2f(k8[e]);
        }
        sc[n][i][j] = dot * 0.125f + ((valid[i] && valid[j]) ? 1.0f : 0.0f);
    }
    __syncthreads();

    // softmax over j (in place)
    if (tid < NHEAD*Ktok) {
        const int n = tid / Ktok, i = tid % Ktok;
        float mx = -1e30f;
        #pragma unroll
        for (int j = 0; j < Ktok; j++) mx = fmaxf(mx, sc[n][i][j]);
        float e[Ktok], sum = 0.f;
        #pragma unroll
        for (int j = 0; j < Ktok; j++) { e[j] = __expf(sc[n][i][j] - mx); sum += e[j]; }
        const float inv = 1.0f / sum;
        #pragma unroll
        for (int j = 0; j < Ktok; j++) sc[n][i][j] = e[j] * inv;
    }
    __syncthreads();

    // cb[j] = sum_{i valid} mean_n attn[n][i][j]   (0 if j invalid)
    if (tid < Ktok) {
        const int j = tid;
        float s = 0.f;
        if (valid[j]) {
            #pragma unroll
            for (int i = 0; i < Ktok; i++) {
                if (!valid[i]) continue;
                #pragma unroll
                for (int n = 0; n < NHEAD; n++) s += sc[n][i][j];
            }
            s *= (1.0f/NHEAD);
        }
        cbS[j] = s;
    }
    __syncthreads();

    if (tid < Ktok) {
        float tot = 0.f;
        #pragma unroll
        for (int j = 0; j < Ktok; j++) tot += cbS[j];
        CW[g*8 + tid] = cbS[tid] / (tot + 1e-8f);
    }
}

// ---------------------------------------------------------------------------
// Kernel 3: single output pass. One block per (b,s) row.
//   valid(g,k) <=> sidx[g,k] == s  (idx==base when mask true, 0 otherwise;
//   s==0 only for w=0,k=0 which is always valid).
// ---------------------------------------------------------------------------
__global__ __launch_bounds__(256) void write_out(
    const float* __restrict__ TE, const float* __restrict__ CW,
    const int* __restrict__ sidx, float* __restrict__ out)
{
    const int rid = blockIdx.x;           // b*Sdim + s
    const int s   = rid & (Sdim - 1);
    const int b   = rid >> 10;
    const int t   = threadIdx.x;
    const int k   = s & 7;
    const int w   = s >> 3;
    float4* dst = (float4*)(out + (size_t)rid * Hdim) + t;

    if (k < Ktok) {
        const int g  = (b << 7) | w;
        const int id = sidx[g*Ktok + k];
        if (id == s) {                    // valid position
            if (k > 0) {                  // absorbed row -> zero
                const float4 z = {0.f, 0.f, 0.f, 0.f};
                *dst = z;
            } else {                      // unified row
                float4 u = {0.f, 0.f, 0.f, 0.f};
                #pragma unroll
                for (int j = 0; j < Ktok; j++) {
                    const float cwj = CW[g*8 + j];
                    if (cwj != 0.f) {
                        const float4 v = *((const float4*)(TE +
                            ((size_t)b*Sdim + sidx[g*Ktok + j])*Hdim) + t);
                        u.x += cwj*v.x; u.y += cwj*v.y;
                        u.z += cwj*v.z; u.w += cwj*v.w;
                    }
                }
                *dst = u;
            }
            return;
        }
    }
    // untouched row -> copy
    *dst = *((const float4*)(TE + (size_t)rid * Hdim) + t);
}

// ---------------------------------------------------------------------------
extern "C" void kernel_launch(void* const* d_in, const int* in_sizes, int n_in,
                              void* d_out, int out_size, void* d_ws, size_t ws_size,
                              hipStream_t stream)
{
    (void)in_sizes; (void)n_in; (void)out_size;
    const float* TE   = (const float*)d_in[0];
    const float* Wt   = (const float*)d_in[1];
    const float* bias = (const float*)d_in[2];
    const int*   sidx = (const int*)d_in[3];
    float*  out  = (float*)d_out;

    // ws layout: Cq (96 MiB) | Xa (48 MiB) | Wb (4 MiB) | CW (128 KiB)
    const size_t CQ_BYTES = (size_t)Mrows * Ncols * 2;
    const size_t XA_BYTES = (size_t)Mrows * Hdim * 2;
    const size_t WB_BYTES = (size_t)Ncols * Hdim * 2;
    const size_t CW_BYTES = (size_t)Lgrp * 8 * 4;
    bf16_t* Cq = (bf16_t*)d_ws;
    bf16_t* Xa = (bf16_t*)((char*)d_ws + CQ_BYTES);
    bf16_t* Wb = (bf16_t*)((char*)d_ws + CQ_BYTES + XA_BYTES);

    dim3 gg(Mrows/128, Ncols/128);  // 192 x 16
    float* CW;
    if (ws_size >= CQ_BYTES + XA_BYTES + WB_BYTES + CW_BYTES) {
        CW = (float*)((char*)d_ws + CQ_BYTES + XA_BYTES + WB_BYTES);
        gather_cvt<<<CVTROWS, 256, 0, stream>>>(TE, Wt, sidx, Xa, Wb);
        gemm_bf16<<<gg, dim3(256), 0, stream>>>(Xa, Wb, bias, Cq);
    } else {
        CW = (float*)((char*)d_ws + CQ_BYTES);
        gemm_qk<<<gg, dim3(256), 0, stream>>>(TE, Wt, bias, sidx, Cq);
    }
    attn_contrib<<<Lgrp, 256, 0, stream>>>(Cq, bias, sidx, CW);
    write_out<<<Bdim*Sdim, 256, 0, stream>>>(TE, CW, sidx, out);
}